// Round 1
// baseline (735.991 us; speedup 1.0000x reference)
//
#include <hip/hip_runtime.h>
#include <hip/hip_bf16.h>

typedef __bf16 bf16_t;
typedef __bf16 bf16x8 __attribute__((ext_vector_type(8)));
typedef float f32x4 __attribute__((ext_vector_type(4)));

__device__ __forceinline__ unsigned short f32_to_bf16_rn(float f) {
  unsigned u = __float_as_uint(f);
  u += 0x7fffu + ((u >> 16) & 1u);
  return (unsigned short)(u >> 16);
}

__device__ __forceinline__ float gelu_exact(float x) {
  return 0.5f * x * (1.0f + erff(x * 0.7071067811865475f));
}

#define GLDS16(g, l)                                                          \
  __builtin_amdgcn_global_load_lds(                                           \
      (const __attribute__((address_space(1))) void*)(g),                     \
      (__attribute__((address_space(3))) void*)(l), 16, 0, 0)

template <bool HASMASK>
__global__ void cast_bf16_kernel(const float* __restrict__ in,
                                 const float* __restrict__ mask,
                                 unsigned short* __restrict__ out, int n4) {
  int i = blockIdx.x * blockDim.x + threadIdx.x;
  if (i >= n4) return;
  float4 v = ((const float4*)in)[i];
  if (HASMASK) {
    float4 m = ((const float4*)mask)[i];
    v.x *= m.x; v.y *= m.y; v.z *= m.z; v.w *= m.w;
  }
  ushort4 o;
  o.x = f32_to_bf16_rn(v.x);
  o.y = f32_to_bf16_rn(v.y);
  o.z = f32_to_bf16_rn(v.z);
  o.w = f32_to_bf16_rn(v.w);
  ((ushort4*)out)[i] = o;
}

// C[M,N] = A[M,K] * B[N,K]^T ; A,B bf16 row-major.
// EPI==1: apply exact gelu, store bf16. EPI==0: store fp32.
template <int EPI>
__global__ void gemm_bt_kernel(const bf16_t* __restrict__ A,
                               const bf16_t* __restrict__ B,
                               void* __restrict__ Cout, int M, int N, int K) {
  __shared__ bf16_t As[128 * 32];
  __shared__ bf16_t Bs[128 * 32];
  const int tid = threadIdx.x;
  const int lane = tid & 63;
  const int wid = tid >> 6;
  const int wm = wid >> 1;
  const int wn = wid & 1;
  const long long brow = (long long)blockIdx.y * 128;
  const long long bcol = (long long)blockIdx.x * 128;

  f32x4 acc[4][4];
#pragma unroll
  for (int i = 0; i < 4; ++i)
#pragma unroll
    for (int j = 0; j < 4; ++j) acc[i][j] = (f32x4){0.f, 0.f, 0.f, 0.f};

  // staging: 256 threads x 16B, two chunks per 128x32 tile (8192 B)
  const int r0 = tid >> 2;          // 0..63
  const int c0 = (tid & 3) * 8;     // 0,8,16,24
  const bf16_t* Ag0 = A + (brow + r0) * (long long)K + c0;
  const bf16_t* Ag1 = A + (brow + 64 + r0) * (long long)K + c0;
  const bf16_t* Bg0 = B + (bcol + r0) * (long long)K + c0;
  const bf16_t* Bg1 = B + (bcol + 64 + r0) * (long long)K + c0;
  bf16_t* Al0 = &As[tid * 8];
  bf16_t* Al1 = &As[2048 + tid * 8];
  bf16_t* Bl0 = &Bs[tid * 8];
  bf16_t* Bl1 = &Bs[2048 + tid * 8];

  const int fr = lane & 15;
  const int fc = (lane >> 4) * 8;

  for (int k0 = 0; k0 < K; k0 += 32) {
    GLDS16(Ag0 + k0, Al0);
    GLDS16(Ag1 + k0, Al1);
    GLDS16(Bg0 + k0, Bl0);
    GLDS16(Bg1 + k0, Bl1);
    __syncthreads();
    bf16x8 af[4], bfr[4];
#pragma unroll
    for (int i = 0; i < 4; ++i) {
      af[i] = *(const bf16x8*)(&As[(wm * 64 + i * 16 + fr) * 32 + fc]);
      bfr[i] = *(const bf16x8*)(&Bs[(wn * 64 + i * 16 + fr) * 32 + fc]);
    }
#pragma unroll
    for (int i = 0; i < 4; ++i)
#pragma unroll
      for (int j = 0; j < 4; ++j)
        acc[i][j] = __builtin_amdgcn_mfma_f32_16x16x32_bf16(af[i], bfr[j],
                                                            acc[i][j], 0, 0, 0);
    __syncthreads();
  }

  const int orow = wm * 64 + (lane >> 4) * 4;
  const int ocol = wn * 64 + (lane & 15);
#pragma unroll
  for (int i = 0; i < 4; ++i)
#pragma unroll
    for (int j = 0; j < 4; ++j)
#pragma unroll
      for (int r = 0; r < 4; ++r) {
        long long row = brow + orow + i * 16 + r;
        long long col = bcol + ocol + j * 16;
        float v = acc[i][j][r];
        if (EPI == 1) {
          ((unsigned short*)Cout)[row * (long long)N + col] =
              f32_to_bf16_rn(gelu_exact(v));
        } else {
          ((float*)Cout)[row * (long long)N + col] = v;
        }
      }
}

extern "C" void kernel_launch(void* const* d_in, const int* in_sizes, int n_in,
                              void* d_out, int out_size, void* d_ws,
                              size_t ws_size, hipStream_t stream) {
  const float* x = (const float*)d_in[0];      // [B,S,D] = [4,2048,2048]
  const float* w1 = (const float*)d_in[1];     // [H,D]   = [8192,2048]
  const float* w2 = (const float*)d_in[2];     // [D,H]   = [2048,8192]
  const float* mask1 = (const float*)d_in[3];  // [H,D]
  const float* mask2 = (const float*)d_in[4];  // [D,H]
  float* out = (float*)d_out;                  // [B,S,D] fp32

  const int D = 2048, H = 8192, M = 8192;  // M = B*S

  unsigned short* xb = (unsigned short*)d_ws;          // M*D bf16
  unsigned short* w1b = xb + (size_t)M * D;            // H*D bf16
  unsigned short* w2b = w1b + (size_t)H * D;           // D*H bf16
  unsigned short* hb = w2b + (size_t)D * H;            // M*H bf16
  // total ws used: (16.78M*3 + 67.1M) * 2B = ~235 MB

  {
    int n4 = (M * D) / 4;  // 4,194,304
    cast_bf16_kernel<false><<<n4 / 256, 256, 0, stream>>>(x, nullptr, xb, n4);
  }
  {
    int n4 = (H * D) / 4;
    cast_bf16_kernel<true><<<n4 / 256, 256, 0, stream>>>(w1, mask1, w1b, n4);
  }
  {
    int n4 = (D * H) / 4;
    cast_bf16_kernel<true><<<n4 / 256, 256, 0, stream>>>(w2, mask2, w2b, n4);
  }

  // h = gelu(x @ sw1^T)  : M=8192, N=H=8192, K=D=2048
  {
    dim3 grid(H / 128, M / 128);
    gemm_bt_kernel<1><<<grid, 256, 0, stream>>>((const bf16_t*)xb,
                                                (const bf16_t*)w1b, hb, M, H, D);
  }
  // out = h @ sw2^T      : M=8192, N=D=2048, K=H=8192
  {
    dim3 grid(D / 128, M / 128);
    gemm_bt_kernel<0><<<grid, 256, 0, stream>>>((const bf16_t*)hb,
                                                (const bf16_t*)w2b, out, M, D, H);
  }
}

// Round 2
// 325.370 us; speedup vs baseline: 2.2620x; 2.2620x over previous
//
#include <hip/hip_runtime.h>
#include <hip/hip_bf16.h>

typedef __bf16 bf16_t;
typedef __bf16 bf16x8 __attribute__((ext_vector_type(8)));
typedef float f32x4 __attribute__((ext_vector_type(4)));

__device__ __forceinline__ unsigned short f32_to_bf16_rn(float f) {
  unsigned u = __float_as_uint(f);
  u += 0x7fffu + ((u >> 16) & 1u);
  return (unsigned short)(u >> 16);
}

__device__ __forceinline__ float gelu_exact(float x) {
  return 0.5f * x * (1.0f + erff(x * 0.7071067811865475f));
}

#define GLDS16(g, l)                                                          \
  __builtin_amdgcn_global_load_lds(                                           \
      (const __attribute__((address_space(1))) void*)(g),                     \
      (__attribute__((address_space(3))) void*)(l), 16, 0, 0)

// ---------------- cast x -> bf16 ----------------
__global__ void cast_x_kernel(const float* __restrict__ in,
                              unsigned short* __restrict__ out, int n4) {
  int i = blockIdx.x * blockDim.x + threadIdx.x;
  if (i >= n4) return;
  float4 v = ((const float4*)in)[i];
  ushort4 o;
  o.x = f32_to_bf16_rn(v.x);
  o.y = f32_to_bf16_rn(v.y);
  o.z = f32_to_bf16_rn(v.z);
  o.w = f32_to_bf16_rn(v.w);
  ((ushort4*)out)[i] = o;
}

// ---------------- build compacted index list (deterministic scan) ----------
// keep j iff mask1 row j nonzero AND mask2 col j nonzero.
// meta[0] = count, meta[1] = Kpad = round_up(count, 128)
__global__ void build_idx_kernel(const float* __restrict__ mask1,
                                 const float* __restrict__ mask2,
                                 int* __restrict__ idx, int* __restrict__ meta,
                                 int H, int D) {
  __shared__ int sums[1024];
  const int t = threadIdx.x;
  int flags[8];
  int tot = 0;
#pragma unroll
  for (int u = 0; u < 8; ++u) {
    int j = t * 8 + u;
    int f = (mask1[(long long)j * D] != 0.0f) && (mask2[j] != 0.0f);
    flags[u] = f;
    tot += f;
  }
  sums[t] = tot;
  __syncthreads();
  for (int off = 1; off < 1024; off <<= 1) {
    int v = (t >= off) ? sums[t - off] : 0;
    __syncthreads();
    sums[t] += v;
    __syncthreads();
  }
  int pos = sums[t] - tot;  // exclusive prefix
#pragma unroll
  for (int u = 0; u < 8; ++u) {
    if (flags[u]) idx[pos++] = t * 8 + u;
  }
  if (t == 1023) {
    int count = sums[1023];
    meta[0] = count;
    meta[1] = (count + 127) & ~127;
  }
}

// ---------------- compact + cast w1 rows: w1c[k,:] = bf16(w1[idx[k],:]) -----
__global__ void compact_w1_kernel(const float* __restrict__ w1,
                                  const int* __restrict__ idx,
                                  const int* __restrict__ meta,
                                  unsigned short* __restrict__ w1c, int D) {
  int q = blockIdx.x * blockDim.x + threadIdx.x;  // quad index
  int k = q >> 9;            // D/4 = 512 quads per row
  int d4 = (q & 511) << 2;
  int count = meta[0];
  ushort4 o = {0, 0, 0, 0};
  if (k < count) {
    int j = idx[k];
    float4 v = *(const float4*)(w1 + (long long)j * D + d4);
    o.x = f32_to_bf16_rn(v.x);
    o.y = f32_to_bf16_rn(v.y);
    o.z = f32_to_bf16_rn(v.z);
    o.w = f32_to_bf16_rn(v.w);
  }
  *(ushort4*)(w1c + (long long)k * D + d4) = o;
}

// ---------------- compact + cast w2 cols: w2c[n,k] = bf16(w2[n,idx[k]]) -----
// w2c leading dim = 4096
__global__ void compact_w2_kernel(const float* __restrict__ w2,
                                  const int* __restrict__ idx,
                                  const int* __restrict__ meta,
                                  unsigned short* __restrict__ w2c, int H) {
  int q = blockIdx.x * blockDim.x + threadIdx.x;  // quad index
  int n = q >> 10;            // 4096/4 = 1024 quads per row
  int k4 = (q & 1023) << 2;
  int count = meta[0];
  ushort4 o = {0, 0, 0, 0};
  unsigned short* dst = w2c + (long long)n * 4096 + k4;
  const float* src = w2 + (long long)n * H;
#pragma unroll
  for (int u = 0; u < 4; ++u) {
    int k = k4 + u;
    unsigned short v = 0;
    if (k < count) v = f32_to_bf16_rn(src[idx[k]]);
    ((unsigned short*)&o)[u] = v;
  }
  *(ushort4*)dst = o;
}

// ---------------- GEMM: C[M,N] = A[M,K] * B[N,K]^T -------------------------
// EPI==1: gelu -> bf16 out (h), early-exit blocks with bcol >= meta[1], K=Kfix
// EPI==0: fp32 out, K = meta[1] (dynamic)
template <int EPI>
__global__ void gemm_bt_kernel(const bf16_t* __restrict__ A,
                               const bf16_t* __restrict__ B,
                               void* __restrict__ Cout, long long ldA,
                               long long ldB, long long ldC, int Kfix,
                               const int* __restrict__ meta) {
  const long long bcol = (long long)blockIdx.x * 128;
  const int kpad = meta[1];
  if (EPI == 1 && bcol >= kpad) return;
  const int K = (EPI == 0) ? kpad : Kfix;

  __shared__ bf16_t As[128 * 32];
  __shared__ bf16_t Bs[128 * 32];
  const int tid = threadIdx.x;
  const int lane = tid & 63;
  const int wid = tid >> 6;
  const int wm = wid >> 1;
  const int wn = wid & 1;
  const long long brow = (long long)blockIdx.y * 128;

  f32x4 acc[4][4];
#pragma unroll
  for (int i = 0; i < 4; ++i)
#pragma unroll
    for (int j = 0; j < 4; ++j) acc[i][j] = (f32x4){0.f, 0.f, 0.f, 0.f};

  const int r0 = tid >> 2;
  const int c0 = (tid & 3) * 8;
  const bf16_t* Ag0 = A + (brow + r0) * ldA + c0;
  const bf16_t* Ag1 = A + (brow + 64 + r0) * ldA + c0;
  const bf16_t* Bg0 = B + (bcol + r0) * ldB + c0;
  const bf16_t* Bg1 = B + (bcol + 64 + r0) * ldB + c0;
  bf16_t* Al0 = &As[tid * 8];
  bf16_t* Al1 = &As[2048 + tid * 8];
  bf16_t* Bl0 = &Bs[tid * 8];
  bf16_t* Bl1 = &Bs[2048 + tid * 8];

  const int fr = lane & 15;
  const int fc = (lane >> 4) * 8;

  for (int k0 = 0; k0 < K; k0 += 32) {
    GLDS16(Ag0 + k0, Al0);
    GLDS16(Ag1 + k0, Al1);
    GLDS16(Bg0 + k0, Bl0);
    GLDS16(Bg1 + k0, Bl1);
    __syncthreads();
    bf16x8 af[4], bfr[4];
#pragma unroll
    for (int i = 0; i < 4; ++i) {
      af[i] = *(const bf16x8*)(&As[(wm * 64 + i * 16 + fr) * 32 + fc]);
      bfr[i] = *(const bf16x8*)(&Bs[(wn * 64 + i * 16 + fr) * 32 + fc]);
    }
#pragma unroll
    for (int i = 0; i < 4; ++i)
#pragma unroll
      for (int j = 0; j < 4; ++j)
        acc[i][j] = __builtin_amdgcn_mfma_f32_16x16x32_bf16(af[i], bfr[j],
                                                            acc[i][j], 0, 0, 0);
    __syncthreads();
  }

  const int orow = wm * 64 + (lane >> 4) * 4;
  const int ocol = wn * 64 + (lane & 15);
#pragma unroll
  for (int i = 0; i < 4; ++i)
#pragma unroll
    for (int j = 0; j < 4; ++j)
#pragma unroll
      for (int r = 0; r < 4; ++r) {
        long long row = brow + orow + i * 16 + r;
        long long col = bcol + ocol + j * 16;
        float v = acc[i][j][r];
        if (EPI == 1) {
          ((unsigned short*)Cout)[row * ldC + col] =
              f32_to_bf16_rn(gelu_exact(v));
        } else {
          ((float*)Cout)[row * ldC + col] = v;
        }
      }
}

extern "C" void kernel_launch(void* const* d_in, const int* in_sizes, int n_in,
                              void* d_out, int out_size, void* d_ws,
                              size_t ws_size, hipStream_t stream) {
  const float* x = (const float*)d_in[0];      // [4,2048,2048]
  const float* w1 = (const float*)d_in[1];     // [8192,2048]
  const float* w2 = (const float*)d_in[2];     // [2048,8192]
  const float* mask1 = (const float*)d_in[3];  // [8192,2048]
  const float* mask2 = (const float*)d_in[4];  // [2048,8192]
  float* out = (float*)d_out;                  // [4,2048,2048] fp32

  const int D = 2048, H = 8192, M = 8192;
  const int KP = 4096;  // worst-case compacted size / leading dim

  char* ws = (char*)d_ws;
  unsigned short* xb = (unsigned short*)ws;                    // M*D bf16
  unsigned short* w1c = xb + (size_t)M * D;                    // KP*D bf16
  unsigned short* w2c = w1c + (size_t)KP * D;                  // D*KP bf16
  unsigned short* hb = w2c + (size_t)D * KP;                   // M*KP bf16
  int* idx = (int*)(hb + (size_t)M * KP);                      // KP ints
  int* meta = idx + KP;                                        // 2 ints

  build_idx_kernel<<<1, 1024, 0, stream>>>(mask1, mask2, idx, meta, H, D);

  {
    int n4 = (M * D) / 4;
    cast_x_kernel<<<n4 / 256, 256, 0, stream>>>(x, xb, n4);
  }
  {
    int nq = KP * (D / 4);  // 2,097,152
    compact_w1_kernel<<<nq / 256, 256, 0, stream>>>(w1, idx, meta, w1c, D);
  }
  {
    int nq = D * (KP / 4);  // 2,097,152
    compact_w2_kernel<<<nq / 256, 256, 0, stream>>>(w2, idx, meta, w2c, H);
  }

  // h[:, 0:Kpad] = gelu(x @ w1c^T): M=8192, N=Kpad (<=4096), K=2048
  {
    dim3 grid(KP / 128, M / 128);
    gemm_bt_kernel<1><<<grid, 256, 0, stream>>>(
        (const bf16_t*)xb, (const bf16_t*)w1c, hb, (long long)D, (long long)D,
        (long long)KP, D, meta);
  }
  // out = h @ w2c^T: M=8192, N=2048, K=Kpad (dynamic)
  {
    dim3 grid(D / 128, M / 128);
    gemm_bt_kernel<0><<<grid, 256, 0, stream>>>(
        (const bf16_t*)hb, (const bf16_t*)w2c, out, (long long)KP,
        (long long)KP, (long long)D, 0, meta);
  }
}

// Round 3
// 292.995 us; speedup vs baseline: 2.5120x; 1.1105x over previous
//
#include <hip/hip_runtime.h>
#include <hip/hip_bf16.h>

typedef __bf16 bf16_t;
typedef __bf16 bf16x8 __attribute__((ext_vector_type(8)));
typedef float f32x4 __attribute__((ext_vector_type(4)));

__device__ __forceinline__ unsigned short f32_to_bf16_rn(float f) {
  unsigned u = __float_as_uint(f);
  u += 0x7fffu + ((u >> 16) & 1u);
  return (unsigned short)(u >> 16);
}

__device__ __forceinline__ float gelu_exact(float x) {
  return 0.5f * x * (1.0f + erff(x * 0.7071067811865475f));
}

// ---------------- cast x -> bf16 ----------------
__global__ void cast_x_kernel(const float* __restrict__ in,
                              unsigned short* __restrict__ out, int n4) {
  int i = blockIdx.x * blockDim.x + threadIdx.x;
  if (i >= n4) return;
  float4 v = ((const float4*)in)[i];
  ushort4 o;
  o.x = f32_to_bf16_rn(v.x);
  o.y = f32_to_bf16_rn(v.y);
  o.z = f32_to_bf16_rn(v.z);
  o.w = f32_to_bf16_rn(v.w);
  ((ushort4*)out)[i] = o;
}

// ---------------- build compacted index list (deterministic scan) ----------
__global__ void build_idx_kernel(const float* __restrict__ mask1,
                                 const float* __restrict__ mask2,
                                 int* __restrict__ idx, int* __restrict__ meta,
                                 int H, int D) {
  __shared__ int sums[1024];
  const int t = threadIdx.x;
  int flags[8];
  int tot = 0;
#pragma unroll
  for (int u = 0; u < 8; ++u) {
    int j = t * 8 + u;
    int f = (mask1[(long long)j * D] != 0.0f) && (mask2[j] != 0.0f);
    flags[u] = f;
    tot += f;
  }
  sums[t] = tot;
  __syncthreads();
  for (int off = 1; off < 1024; off <<= 1) {
    int v = (t >= off) ? sums[t - off] : 0;
    __syncthreads();
    sums[t] += v;
    __syncthreads();
  }
  int pos = sums[t] - tot;
#pragma unroll
  for (int u = 0; u < 8; ++u) {
    if (flags[u]) idx[pos++] = t * 8 + u;
  }
  if (t == 1023) {
    int count = sums[1023];
    meta[0] = count;
    meta[1] = (count + 127) & ~127;
  }
}

// ---------------- compact + cast w1 rows ----------------
__global__ void compact_w1_kernel(const float* __restrict__ w1,
                                  const int* __restrict__ idx,
                                  const int* __restrict__ meta,
                                  unsigned short* __restrict__ w1c, int D) {
  int q = blockIdx.x * blockDim.x + threadIdx.x;
  int k = q >> 9;
  int d4 = (q & 511) << 2;
  int count = meta[0];
  ushort4 o = {0, 0, 0, 0};
  if (k < count) {
    int j = idx[k];
    float4 v = *(const float4*)(w1 + (long long)j * D + d4);
    o.x = f32_to_bf16_rn(v.x);
    o.y = f32_to_bf16_rn(v.y);
    o.z = f32_to_bf16_rn(v.z);
    o.w = f32_to_bf16_rn(v.w);
  }
  *(ushort4*)(w1c + (long long)k * D + d4) = o;
}

// ---------------- compact + cast w2 cols (ld 4096) ----------------
__global__ void compact_w2_kernel(const float* __restrict__ w2,
                                  const int* __restrict__ idx,
                                  const int* __restrict__ meta,
                                  unsigned short* __restrict__ w2c, int H) {
  int q = blockIdx.x * blockDim.x + threadIdx.x;
  int n = q >> 10;
  int k4 = (q & 1023) << 2;
  int count = meta[0];
  ushort4 o = {0, 0, 0, 0};
  const float* src = w2 + (long long)n * H;
#pragma unroll
  for (int u = 0; u < 4; ++u) {
    int k = k4 + u;
    unsigned short v = 0;
    if (k < count) v = f32_to_bf16_rn(src[idx[k]]);
    ((unsigned short*)&o)[u] = v;
  }
  *(ushort4*)(w2c + (long long)n * 4096 + k4) = o;
}

// ================= 256x256 8-phase GEMM (T2+T3+T4+T5) ======================
// C[M,N] = A[M,K] * B[N,K]^T, bf16 in. BM=BN=256, BK=64, 8 waves (2Mx4N).
// LDS 128KB: 2 dbuf x {A,B} x [256 rows][64 cols] bf16, XOR-swizzled
// (granule ^= row&7 within each 128B row; inverse applied on gl_lds source).
// EPI==1: gelu->bf16, early-exit bcol>=kpad, K=Kfix. EPI==0: fp32, K=kpad.

#define BUF_STRIDE 65536
#define BREG_OFF 32768
#define HALF_STRIDE 16384
#define WAVE_STRIDE 2048
#define INST_STRIDE 1024

#define STAGE_A(c, h, i, k0)                                                   \
  __builtin_amdgcn_global_load_lds(                                            \
      (const __attribute__((address_space(1))) void*)(Asrc +                   \
          ((h) * 128 + (i) * 8) * ldA + (k0)),                                 \
      (__attribute__((address_space(3))) void*)(&smem[(c) * BUF_STRIDE +       \
          (h) * HALF_STRIDE + w * WAVE_STRIDE + (i) * INST_STRIDE]),           \
      16, 0, 0)

#define STAGE_B(c, h, i, k0)                                                   \
  __builtin_amdgcn_global_load_lds(                                            \
      (const __attribute__((address_space(1))) void*)(Bsrc +                   \
          ((h) * 128 + (i) * 8) * ldB + (k0)),                                 \
      (__attribute__((address_space(3))) void*)(&smem[(c) * BUF_STRIDE +       \
          BREG_OFF + (h) * HALF_STRIDE + w * WAVE_STRIDE + (i) * INST_STRIDE]),\
      16, 0, 0)

template <int EPI>
__global__ __launch_bounds__(512, 2) void gemm256_kernel(
    const bf16_t* __restrict__ A, const bf16_t* __restrict__ B,
    void* __restrict__ Cout, long long ldA, long long ldB, long long ldC,
    int Kfix, const int* __restrict__ meta) {
  const int kpad = meta[1];
  // bijective XCD swizzle (grid counts are multiples of 8)
  const int nwg = gridDim.x * gridDim.y;
  const int bid = blockIdx.y * gridDim.x + blockIdx.x;
  const int swz = (bid & 7) * (nwg >> 3) + (bid >> 3);
  const int bx = swz % gridDim.x;
  const int by = swz / gridDim.x;
  const long long brow = (long long)by * 256;
  const long long bcol = (long long)bx * 256;
  if (EPI == 1 && bcol >= kpad) return;
  const int K = (EPI == 0) ? kpad : Kfix;
  const int NT = K >> 6;

  __shared__ __align__(16) char smem[131072];

  const int tid = threadIdx.x;
  const int l = tid & 63;
  const int w = tid >> 6;   // wave 0..7
  const int wm = w >> 2;    // 0..1
  const int wn = w & 3;     // 0..3

  // ---- staging addresses (per-lane global src, inverse-swizzled column) ----
  const int srow = w * 16 + (l >> 3);            // 0..127 within a half
  const int sgran = (l & 7) ^ (l >> 3);          // source granule (8 bf16)
  const bf16_t* Asrc = A + (brow + srow) * ldA + sgran * 8;
  const bf16_t* Bsrc = B + (bcol + srow) * ldB + sgran * 8;

  // ---- swizzled ds_read offsets ----
  const int g0 = (l >> 4) ^ (l & 7);
  const int aoff = (wm * 128 + (l & 15)) * 128 + g0 * 16;
  const int boff = BREG_OFF + (wn * 64 + (l & 15)) * 128 + g0 * 16;

  f32x4 acc[8][4];
#pragma unroll
  for (int m = 0; m < 8; ++m)
#pragma unroll
    for (int n = 0; n < 4; ++n) acc[m][n] = (f32x4){0.f, 0.f, 0.f, 0.f};

  bf16x8 a[4][2], b[4][2];

  // ---- prologue: tile0 full, tile1 A-halves ----
  STAGE_A(0, 0, 0, 0); STAGE_A(0, 0, 1, 0); STAGE_A(0, 1, 0, 0); STAGE_A(0, 1, 1, 0);
  STAGE_B(0, 0, 0, 0); STAGE_B(0, 0, 1, 0); STAGE_B(0, 1, 0, 0); STAGE_B(0, 1, 1, 0);
  STAGE_A(1, 0, 0, 64); STAGE_A(1, 0, 1, 64); STAGE_A(1, 1, 0, 64); STAGE_A(1, 1, 1, 64);
  asm volatile("s_waitcnt vmcnt(4)" ::: "memory");
  __builtin_amdgcn_s_barrier();

  for (int t = 0; t < NT; ++t) {
    const int c = t & 1;
    const int cb = c * BUF_STRIDE;
    const int k1 = (t + 1) << 6;
    const int k2 = (t + 2) << 6;

    // ===== phase 0: B-halves of tile t+1; reads A[0-3],B[0-1]; MFMA q0 =====
    if (t + 1 < NT) {
      STAGE_B(c ^ 1, 0, 0, k1); STAGE_B(c ^ 1, 0, 1, k1);
      STAGE_B(c ^ 1, 1, 0, k1); STAGE_B(c ^ 1, 1, 1, k1);
    }
#pragma unroll
    for (int m = 0; m < 4; ++m)
#pragma unroll
      for (int kk = 0; kk < 2; ++kk)
        a[m][kk] = *(const bf16x8*)&smem[cb + ((aoff + m * 2048) ^ (kk * 64))];
#pragma unroll
    for (int n = 0; n < 2; ++n)
#pragma unroll
      for (int kk = 0; kk < 2; ++kk)
        b[n][kk] = *(const bf16x8*)&smem[cb + ((boff + n * 2048) ^ (kk * 64))];
    __builtin_amdgcn_s_barrier();
    __builtin_amdgcn_s_setprio(1);
#pragma unroll
    for (int m = 0; m < 4; ++m)
#pragma unroll
      for (int n = 0; n < 2; ++n)
#pragma unroll
        for (int kk = 0; kk < 2; ++kk)
          acc[m][n] = __builtin_amdgcn_mfma_f32_16x16x32_bf16(
              a[m][kk], b[n][kk], acc[m][n], 0, 0, 0);
    __builtin_amdgcn_s_setprio(0);
    __builtin_amdgcn_s_barrier();

    // ===== phase 1: reads B[2-3]; MFMA q1 =====
#pragma unroll
    for (int n = 2; n < 4; ++n)
#pragma unroll
      for (int kk = 0; kk < 2; ++kk)
        b[n][kk] = *(const bf16x8*)&smem[cb + ((boff + n * 2048) ^ (kk * 64))];
    __builtin_amdgcn_s_barrier();
    __builtin_amdgcn_s_setprio(1);
#pragma unroll
    for (int m = 0; m < 4; ++m)
#pragma unroll
      for (int n = 2; n < 4; ++n)
#pragma unroll
        for (int kk = 0; kk < 2; ++kk)
          acc[m][n] = __builtin_amdgcn_mfma_f32_16x16x32_bf16(
              a[m][kk], b[n][kk], acc[m][n], 0, 0, 0);
    __builtin_amdgcn_s_setprio(0);
    __builtin_amdgcn_s_barrier();

    // ===== phase 2: reads A[4-7]; MFMA q2 =====
#pragma unroll
    for (int m = 0; m < 4; ++m)
#pragma unroll
      for (int kk = 0; kk < 2; ++kk)
        a[m][kk] =
            *(const bf16x8*)&smem[cb + ((aoff + (m + 4) * 2048) ^ (kk * 64))];
    __builtin_amdgcn_s_barrier();
    __builtin_amdgcn_s_setprio(1);
#pragma unroll
    for (int m = 0; m < 4; ++m)
#pragma unroll
      for (int n = 0; n < 2; ++n)
#pragma unroll
        for (int kk = 0; kk < 2; ++kk)
          acc[m + 4][n] = __builtin_amdgcn_mfma_f32_16x16x32_bf16(
              a[m][kk], b[n][kk], acc[m + 4][n], 0, 0, 0);
    __builtin_amdgcn_s_setprio(0);
    __builtin_amdgcn_s_barrier();

    // ===== phase 3: A-halves of tile t+2; counted vmcnt; MFMA q3 =====
    if (t + 2 < NT) {
      STAGE_A(c, 0, 0, k2); STAGE_A(c, 0, 1, k2);
      STAGE_A(c, 1, 0, k2); STAGE_A(c, 1, 1, k2);
      asm volatile("s_waitcnt vmcnt(4)" ::: "memory");
    } else if (t + 1 < NT) {
      asm volatile("s_waitcnt vmcnt(0)" ::: "memory");
    }
    __builtin_amdgcn_s_barrier();
    __builtin_amdgcn_s_setprio(1);
#pragma unroll
    for (int m = 0; m < 4; ++m)
#pragma unroll
      for (int n = 2; n < 4; ++n)
#pragma unroll
        for (int kk = 0; kk < 2; ++kk)
          acc[m + 4][n] = __builtin_amdgcn_mfma_f32_16x16x32_bf16(
              a[m][kk], b[n][kk], acc[m + 4][n], 0, 0, 0);
    __builtin_amdgcn_s_setprio(0);
    __builtin_amdgcn_s_barrier();
  }

  // ---- epilogue ----
  const int orow = wm * 128 + ((l >> 4) << 2);
  const int ocol = wn * 64 + (l & 15);
#pragma unroll
  for (int m = 0; m < 8; ++m)
#pragma unroll
    for (int n = 0; n < 4; ++n)
#pragma unroll
      for (int r = 0; r < 4; ++r) {
        long long row = brow + orow + m * 16 + r;
        long long col = bcol + ocol + n * 16;
        float v = acc[m][n][r];
        if (EPI == 1) {
          ((unsigned short*)Cout)[row * ldC + col] =
              f32_to_bf16_rn(gelu_exact(v));
        } else {
          ((float*)Cout)[row * ldC + col] = v;
        }
      }
}

extern "C" void kernel_launch(void* const* d_in, const int* in_sizes, int n_in,
                              void* d_out, int out_size, void* d_ws,
                              size_t ws_size, hipStream_t stream) {
  const float* x = (const float*)d_in[0];
  const float* w1 = (const float*)d_in[1];
  const float* w2 = (const float*)d_in[2];
  const float* mask1 = (const float*)d_in[3];
  const float* mask2 = (const float*)d_in[4];
  float* out = (float*)d_out;

  const int D = 2048, H = 8192, M = 8192;
  const int KP = 4096;

  char* ws = (char*)d_ws;
  unsigned short* xb = (unsigned short*)ws;
  unsigned short* w1c = xb + (size_t)M * D;
  unsigned short* w2c = w1c + (size_t)KP * D;
  unsigned short* hb = w2c + (size_t)D * KP;
  int* idx = (int*)(hb + (size_t)M * KP);
  int* meta = idx + KP;

  build_idx_kernel<<<1, 1024, 0, stream>>>(mask1, mask2, idx, meta, H, D);

  {
    int n4 = (M * D) / 4;
    cast_x_kernel<<<n4 / 256, 256, 0, stream>>>(x, xb, n4);
  }
  {
    int nq = KP * (D / 4);
    compact_w1_kernel<<<nq / 256, 256, 0, stream>>>(w1, idx, meta, w1c, D);
  }
  {
    int nq = D * (KP / 4);
    compact_w2_kernel<<<nq / 256, 256, 0, stream>>>(w2, idx, meta, w2c, H);
  }

  // h[:, 0:kpad] = gelu(x @ w1c^T): M=8192, N<=4096 (early-exit), K=2048
  {
    dim3 grid(KP / 256, M / 256);  // 16 x 32 = 512 blocks
    gemm256_kernel<1><<<grid, 512, 0, stream>>>(
        (const bf16_t*)xb, (const bf16_t*)w1c, hb, (long long)D, (long long)D,
        (long long)KP, D, meta);
  }
  // out = h @ w2c^T: M=8192, N=2048, K=kpad (dynamic)
  {
    dim3 grid(D / 256, M / 256);  // 8 x 32 = 256 blocks
    gemm256_kernel<0><<<grid, 512, 0, stream>>>(
        (const bf16_t*)hb, (const bf16_t*)w2c, out, (long long)KP,
        (long long)KP, (long long)D, 0, meta);
  }
}